// Round 9
// baseline (190.837 us; speedup 1.0000x reference)
//
#include <hip/hip_runtime.h>
#include <stdint.h>

// Problem constants: B=32, S=10, D=4096, K=8192
#define B_ 32
#define S_ 10
#define D_ 4096
#define K_ 8192
#define RPB 21                 // rows per batch in A: 10 pq + 10 pp + 1 qq
#define M_REAL (B_ * RPB)      // 672

#define BM 128
#define BN 128
#define BK 32
#define M_PAD_MF 768           // 6 tiles of 128
#define KSPLIT 4
#define KCHUNK (D_ / KSPLIT)   // 1024
#define NSTEP (KCHUNK / BK)    // 32

typedef _Float16 f16x8 __attribute__((ext_vector_type(8)));
typedef float f32x4 __attribute__((ext_vector_type(4)));
typedef unsigned short us4 __attribute__((ext_vector_type(4)));

__device__ __forceinline__ void async16(const void* g, void* l) {
  __builtin_amdgcn_global_load_lds(
      (const __attribute__((address_space(1))) unsigned int*)g,
      (__attribute__((address_space(3))) unsigned int*)l, 16, 0, 0);
}

// ---------------------------------------------------------------------------
// Prepass: build A rows (pq / pp / qq), quantize to a single f16 plane.
// ---------------------------------------------------------------------------
__global__ __launch_bounds__(256)
void build_a_f16(const float* __restrict__ p, const float* __restrict__ q,
                 unsigned short* __restrict__ Af) {
  size_t idx = (size_t)blockIdx.x * 256 + threadIdx.x;  // over M_PAD_MF * 1024 float4s
  int d4 = (int)(idx & 1023);
  int m = (int)(idx >> 10);
  float4 v = make_float4(0.f, 0.f, 0.f, 0.f);
  if (m < M_REAL) {
    int b = m / RPB;
    int r = m - b * RPB;
    const float4* q4 = (const float4*)(q + (size_t)(b * S_ + (S_ - 1)) * D_);
    if (r < S_) {
      const float4* p4 = (const float4*)(p + (size_t)(b * S_ + r) * D_);
      float4 pv = p4[d4]; float4 qv = q4[d4];
      v = make_float4(pv.x * qv.x, pv.y * qv.y, pv.z * qv.z, pv.w * qv.w);
    } else if (r < 2 * S_) {
      const float4* p4 = (const float4*)(p + (size_t)(b * S_ + (r - S_)) * D_);
      float4 pv = p4[d4];
      v = make_float4(pv.x * pv.x, pv.y * pv.y, pv.z * pv.z, pv.w * pv.w);
    } else {
      float4 qv = q4[d4];
      v = make_float4(qv.x * qv.x, qv.y * qv.y, qv.z * qv.z, qv.w * qv.w);
    }
  }
  us4 h;
  ((unsigned short*)&h)[0] = (unsigned short)__builtin_bit_cast(unsigned short, (_Float16)v.x);
  ((unsigned short*)&h)[1] = (unsigned short)__builtin_bit_cast(unsigned short, (_Float16)v.y);
  ((unsigned short*)&h)[2] = (unsigned short)__builtin_bit_cast(unsigned short, (_Float16)v.z);
  ((unsigned short*)&h)[3] = (unsigned short)__builtin_bit_cast(unsigned short, (_Float16)v.w);
  ((us4*)Af)[idx] = h;
}

// ---------------------------------------------------------------------------
// Fused MFMA GEMM: G[ks][m][k] = sum_{d in chunk ks} Af[m][d] * (W[k][d])^2
// R6 body (full double-buffer, ONE __syncthreads per step), KSPLIT=4 for TLP:
// 1536 blocks -> 5 blocks/CU resident (LDS-limited), 20 waves/CU, so stalled
// barrier-groups are hidden by other blocks' waves.
// 16B-chunk XOR swizzle  phys_chunk = chunk ^ ((row^(row>>2))&3) on all tiles.
// ---------------------------------------------------------------------------
__global__ __launch_bounds__(256, 5)
void gemm_mfma(const unsigned short* __restrict__ Af, const float* __restrict__ W,
               float* __restrict__ G) {
  __shared__ unsigned short lds[4 * 128 * 32];   // 32 KB
  const int tid = threadIdx.x;
  const int lane = tid & 63;
  const int wid = tid >> 6;
  const int m0 = blockIdx.y * BM;
  const int n0 = blockIdx.x * BN;
  const int ks = blockIdx.z;
  const int d_base = ks * KCHUNK;

  char* const ldsb = (char*)lds;          // A buffers at 0, 8192
  char* const ldsWb = ldsb + 16384;       // W buffers at 16384, 24576

  // ---- A staging: 2 async DMA issues per k-step, pre-swizzled global src ----
  const unsigned short* gpA[2];
  uint32_t ldsoffA[2];                    // within an A buffer (0..8K)
#pragma unroll
  for (int half = 0; half < 2; ++half) {
    int row = half * 64 + wid * 16 + (lane >> 2);
    int k16l = (lane & 3) ^ ((row ^ (row >> 2)) & 3);
    gpA[half] = Af + (size_t)(m0 + row) * D_ + d_base + k16l * 8;
    ldsoffA[half] = (uint32_t)(half * 4096 + wid * 1024);   // bytes
  }

  // ---- W staging: thread t covers row=t>>1, floats [h*16, h*16+16) ----
  const int wrow = tid >> 1;
  const int wh = tid & 1;
  const float* gW = W + (size_t)(n0 + wrow) * D_ + d_base + wh * 16;
  const int wsz = (wrow ^ (wrow >> 2)) & 3;
  const uint32_t wbyte0 = (uint32_t)(wrow * 64 + ((2 * wh) ^ wsz) * 16);
  const uint32_t wbyte1 = (uint32_t)(wrow * 64 + ((2 * wh + 1) ^ wsz) * 16);

  f32x4 acc[4][4];
#pragma unroll
  for (int i = 0; i < 4; ++i)
#pragma unroll
    for (int j = 0; j < 4; ++j) acc[i][j] = (f32x4){0.f, 0.f, 0.f, 0.f};

  const int wm = wid >> 1;        // wave row in 2x2 grid
  const int wn = wid & 1;
  const int frow = lane & 15;
  const int k16 = lane >> 4;
  int aoff[4], woff[4];           // byte offsets of fragments within a tile
#pragma unroll
  for (int f = 0; f < 4; ++f) {
    int ra = wm * 64 + f * 16 + frow;
    aoff[f] = ra * 64 + ((k16 ^ ((ra ^ (ra >> 2)) & 3)) * 16);
    int rw = wn * 64 + f * 16 + frow;
    woff[f] = rw * 64 + ((k16 ^ ((rw ^ (rw >> 2)) & 3)) * 16);
  }

  // ---- prologue: stage step 0 (A via DMA, W via reg+cvt), exposed once ----
  async16(gpA[0], ldsb + ldsoffA[0]);
  async16(gpA[1], ldsb + ldsoffA[1]);
  {
    float4 w0 = *(const float4*)(gW);
    float4 w1 = *(const float4*)(gW + 4);
    float4 w2 = *(const float4*)(gW + 8);
    float4 w3 = *(const float4*)(gW + 12);
    f16x8 o0, o1;
    o0[0] = (_Float16)(w0.x * w0.x); o0[1] = (_Float16)(w0.y * w0.y);
    o0[2] = (_Float16)(w0.z * w0.z); o0[3] = (_Float16)(w0.w * w0.w);
    o0[4] = (_Float16)(w1.x * w1.x); o0[5] = (_Float16)(w1.y * w1.y);
    o0[6] = (_Float16)(w1.z * w1.z); o0[7] = (_Float16)(w1.w * w1.w);
    o1[0] = (_Float16)(w2.x * w2.x); o1[1] = (_Float16)(w2.y * w2.y);
    o1[2] = (_Float16)(w2.z * w2.z); o1[3] = (_Float16)(w2.w * w2.w);
    o1[4] = (_Float16)(w3.x * w3.x); o1[5] = (_Float16)(w3.y * w3.y);
    o1[6] = (_Float16)(w3.z * w3.z); o1[7] = (_Float16)(w3.w * w3.w);
    *(f16x8*)(ldsWb + wbyte0) = o0;
    *(f16x8*)(ldsWb + wbyte1) = o1;
  }
  __syncthreads();   // step-0 tiles visible

  for (int i = 0; i < NSTEP; ++i) {
    // ---- top: prefetch step i+1 (A-DMA + W fp32 regs) into the idle bufs ----
    const int dn = ((i + 1 < NSTEP) ? (i + 1) : i) * BK;   // clamped (safe reload)
    const uint32_t nb = (uint32_t)(((i + 1) & 1) * 8192);
    async16(gpA[0] + dn, ldsb + nb + ldsoffA[0]);
    async16(gpA[1] + dn, ldsb + nb + ldsoffA[1]);
    float4 w0 = *(const float4*)(gW + dn);
    float4 w1 = *(const float4*)(gW + dn + 4);
    float4 w2 = *(const float4*)(gW + dn + 8);
    float4 w3 = *(const float4*)(gW + dn + 12);

    // ---- compute step i from buf[i&1] ----
    const uint32_t cb = (uint32_t)((i & 1) * 8192);
    f16x8 aF[4];
#pragma unroll
    for (int f = 0; f < 4; ++f)
      aF[f] = *(const f16x8*)(ldsb + cb + aoff[f]);
#pragma unroll
    for (int nf = 0; nf < 4; ++nf) {
      f16x8 wF = *(const f16x8*)(ldsWb + cb + woff[nf]);
#pragma unroll
      for (int mf = 0; mf < 4; ++mf)
        acc[mf][nf] = __builtin_amdgcn_mfma_f32_16x16x32_f16(aF[mf], wF, acc[mf][nf], 0, 0, 0);
    }

    // ---- bottom: cvt + ds_write W(i+1) into Wbuf[!cur] ----
    f16x8 o0, o1;
    o0[0] = (_Float16)(w0.x * w0.x); o0[1] = (_Float16)(w0.y * w0.y);
    o0[2] = (_Float16)(w0.z * w0.z); o0[3] = (_Float16)(w0.w * w0.w);
    o0[4] = (_Float16)(w1.x * w1.x); o0[5] = (_Float16)(w1.y * w1.y);
    o0[6] = (_Float16)(w1.z * w1.z); o0[7] = (_Float16)(w1.w * w1.w);
    o1[0] = (_Float16)(w2.x * w2.x); o1[1] = (_Float16)(w2.y * w2.y);
    o1[2] = (_Float16)(w2.z * w2.z); o1[3] = (_Float16)(w2.w * w2.w);
    o1[4] = (_Float16)(w3.x * w3.x); o1[5] = (_Float16)(w3.y * w3.y);
    o1[6] = (_Float16)(w3.z * w3.z); o1[7] = (_Float16)(w3.w * w3.w);
    *(f16x8*)(ldsWb + nb + wbyte0) = o0;
    *(f16x8*)(ldsWb + nb + wbyte1) = o1;

    __syncthreads();   // single barrier: step i+1 tiles ready, step i reads done
  }

  // ---- C write: row=(lane>>4)*4+r, col=lane&15 (verified gfx950 C/D layout) ----
  float* Gp = G + (size_t)ks * M_PAD_MF * K_;
  const int crow = m0 + wm * 64;
  const int ccol = n0 + wn * 64;
#pragma unroll
  for (int mf = 0; mf < 4; ++mf)
#pragma unroll
    for (int nf = 0; nf < 4; ++nf)
#pragma unroll
      for (int r = 0; r < 4; ++r) {
        int row = crow + mf * 16 + (lane >> 4) * 4 + r;
        int col = ccol + nf * 16 + (lane & 15);
        Gp[(size_t)row * K_ + col] = acc[mf][nf][r];
      }
}

// ---------------------------------------------------------------------------
// Epilogue: sum 4 K-split planes, normalize, transpose-write.
// out[b][k][s] = -dot / (sqrt(pp)*sqrt(qq)*D)
// ---------------------------------------------------------------------------
__global__ __launch_bounds__(256)
void epilogue4(const float* __restrict__ G, float* __restrict__ out) {
  __shared__ float buf[256 * S_];
  const int tid = threadIdx.x;
  const int b = blockIdx.y;
  const int k0 = blockIdx.x * 256;
  const int k = k0 + tid;
  const size_t PL = (size_t)M_PAD_MF * K_;
  const float* Gb = G + (size_t)b * RPB * K_ + k;
  float nq = sqrtf(Gb[20 * K_] + Gb[PL + 20 * K_] + Gb[2 * PL + 20 * K_] + Gb[3 * PL + 20 * K_]);
#pragma unroll
  for (int s = 0; s < S_; ++s) {
    size_t od = (size_t)s * K_;
    size_t op = (size_t)(S_ + s) * K_;
    float dot = Gb[od] + Gb[PL + od] + Gb[2 * PL + od] + Gb[3 * PL + od];
    float pp  = Gb[op] + Gb[PL + op] + Gb[2 * PL + op] + Gb[3 * PL + op];
    buf[tid * S_ + s] = -dot / (sqrtf(pp) * nq * (float)D_);
  }
  __syncthreads();
  float* ob = out + ((size_t)b * K_ + k0) * S_;
  for (int i = tid; i < 256 * S_; i += 256) ob[i] = buf[i];
}

// ===========================================================================
extern "C" void kernel_launch(void* const* d_in, const int* in_sizes, int n_in,
                              void* d_out, int out_size, void* d_ws, size_t ws_size,
                              hipStream_t stream) {
  const float* p = (const float*)d_in[0];
  const float* q = (const float*)d_in[1];
  const float* W = (const float*)d_in[2];
  float* out = (float*)d_out;

  // ws layout: Af [768][4096] f16 (6291456 B) | G [4][768][8192] f32 (100663296 B)
  uint8_t* w = (uint8_t*)d_ws;
  unsigned short* Af = (unsigned short*)w;
  float* G = (float*)(w + 6291456);

  build_a_f16<<<(M_PAD_MF * (D_ / 4)) / 256, 256, 0, stream>>>(p, q, Af);
  dim3 ggrid(K_ / BN, M_PAD_MF / BM, KSPLIT);   // (64, 6, 4) = 1536 blocks ≈ 5/CU
  gemm_mfma<<<ggrid, 256, 0, stream>>>(Af, W, G);
  epilogue4<<<dim3(K_ / 256, B_), 256, 0, stream>>>(G, out);
}

// Round 10
// 128.047 us; speedup vs baseline: 1.4904x; 1.4904x over previous
//
#include <hip/hip_runtime.h>
#include <stdint.h>

// Problem constants: B=32, S=10, D=4096, K=8192
#define B_ 32
#define S_ 10
#define D_ 4096
#define K_ 8192
#define RPB 21                 // rows per batch in A: 10 pq + 10 pp + 1 qq
#define M_REAL (B_ * RPB)      // 672

#define BM 128
#define BN 128
#define BK 32
#define M_PAD_MF 768           // 6 tiles of 128
#define KSPLIT 2
#define KHALF (D_ / KSPLIT)    // 2048
#define NSTEP (KHALF / BK)     // 64

typedef _Float16 f16x8 __attribute__((ext_vector_type(8)));
typedef float f32x4 __attribute__((ext_vector_type(4)));
typedef unsigned short us4 __attribute__((ext_vector_type(4)));

__device__ __forceinline__ void async16(const void* g, void* l) {
  __builtin_amdgcn_global_load_lds(
      (const __attribute__((address_space(1))) unsigned int*)g,
      (__attribute__((address_space(3))) unsigned int*)l, 16, 0, 0);
}

// ---------------------------------------------------------------------------
// Prepass: build A rows (pq / pp / qq), quantize to a single f16 plane.
// ---------------------------------------------------------------------------
__global__ __launch_bounds__(256)
void build_a_f16(const float* __restrict__ p, const float* __restrict__ q,
                 unsigned short* __restrict__ Af) {
  size_t idx = (size_t)blockIdx.x * 256 + threadIdx.x;  // over M_PAD_MF * 1024 float4s
  int d4 = (int)(idx & 1023);
  int m = (int)(idx >> 10);
  float4 v = make_float4(0.f, 0.f, 0.f, 0.f);
  if (m < M_REAL) {
    int b = m / RPB;
    int r = m - b * RPB;
    const float4* q4 = (const float4*)(q + (size_t)(b * S_ + (S_ - 1)) * D_);
    if (r < S_) {
      const float4* p4 = (const float4*)(p + (size_t)(b * S_ + r) * D_);
      float4 pv = p4[d4]; float4 qv = q4[d4];
      v = make_float4(pv.x * qv.x, pv.y * qv.y, pv.z * qv.z, pv.w * qv.w);
    } else if (r < 2 * S_) {
      const float4* p4 = (const float4*)(p + (size_t)(b * S_ + (r - S_)) * D_);
      float4 pv = p4[d4];
      v = make_float4(pv.x * pv.x, pv.y * pv.y, pv.z * pv.z, pv.w * pv.w);
    } else {
      float4 qv = q4[d4];
      v = make_float4(qv.x * qv.x, qv.y * qv.y, qv.z * qv.z, qv.w * qv.w);
    }
  }
  us4 h;
  ((unsigned short*)&h)[0] = (unsigned short)__builtin_bit_cast(unsigned short, (_Float16)v.x);
  ((unsigned short*)&h)[1] = (unsigned short)__builtin_bit_cast(unsigned short, (_Float16)v.y);
  ((unsigned short*)&h)[2] = (unsigned short)__builtin_bit_cast(unsigned short, (_Float16)v.z);
  ((unsigned short*)&h)[3] = (unsigned short)__builtin_bit_cast(unsigned short, (_Float16)v.w);
  ((us4*)Af)[idx] = h;
}

// ---------------------------------------------------------------------------
// Fused MFMA GEMM: G[ks][m][k] = sum_{d in half ks} Af[m][d] * (W[k][d])^2
// ALL-async staging (no reg round-trip anywhere):
//   A (f16): global_load_lds, 2 issues/thread/step, pre-swizzled source.
//   W (f32): global_load_lds DIRECT from the fp32 input, 4 issues/thread/step,
//            pre-swizzled source.  Square + f16-convert happen at FRAGMENT
//            READ time (2x ds_read_b128 f32 + 8 mul + 8 cvt per B-frag) —
//            VALU co-issues with the MFMA pipe, no prepass, no ds_write.
// Full double-buffer both operands, ONE __syncthreads per step (R6 skeleton).
// LDS 48 KB: Abuf0 @0 (8K) | Abuf1 @8K | Wbuf0 @16K (16K) | Wbuf1 @32K
//   -> 3 blocks/CU (LDS-limited), VGPR capped 128 -> 4 waves/SIMD, no spill.
// Swizzles (involutions, applied to DMA source and frag reads):
//   A row = 64 B  = 4 granules:  phys = g ^ ((row ^ (row>>2)) & 3)
//   W row = 128 B = 8 granules:  phys = g ^ (row & 7)
// ---------------------------------------------------------------------------
__global__ __launch_bounds__(256, 4)
void gemm_mfma(const unsigned short* __restrict__ Af, const float* __restrict__ W,
               float* __restrict__ G) {
  __shared__ unsigned short lds[24576];   // 48 KB
  const int tid = threadIdx.x;
  const int lane = tid & 63;
  const int wid = tid >> 6;
  const int m0 = blockIdx.y * BM;
  const int n0 = blockIdx.x * BN;
  const int ks = blockIdx.z;
  const int d_base = ks * KHALF;

  char* const ldsb = (char*)lds;          // A buffers at 0, 8192
  char* const ldsWf = ldsb + 16384;       // W f32 buffers at 0, 16384 (rel)

  // ---- A staging: 2 async DMA issues per k-step, pre-swizzled global src ----
  const unsigned short* gpA[2];
  uint32_t ldsoffA[2];                    // within an A buffer (0..8K)
#pragma unroll
  for (int half = 0; half < 2; ++half) {
    int row = half * 64 + wid * 16 + (lane >> 2);
    int g = (lane & 3) ^ ((row ^ (row >> 2)) & 3);
    gpA[half] = Af + (size_t)(m0 + row) * D_ + d_base + g * 8;
    ldsoffA[half] = (uint32_t)(half * 4096 + wid * 1024);   // bytes
  }

  // ---- W staging: 4 async DMA issues per thread (16 KB fp32 tile) ----
  const float* gpW[4];
  uint32_t ldsoffW[4];                    // within a W buffer (0..16K)
#pragma unroll
  for (int e = 0; e < 4; ++e) {
    int row = wid * 32 + e * 8 + (lane >> 3);
    int g = (lane & 7) ^ (row & 7);
    gpW[e] = W + (size_t)(n0 + row) * D_ + d_base + g * 4;
    ldsoffW[e] = (uint32_t)((wid * 4 + e) * 1024);
  }

  f32x4 acc[4][4];
#pragma unroll
  for (int i = 0; i < 4; ++i)
#pragma unroll
    for (int j = 0; j < 4; ++j) acc[i][j] = (f32x4){0.f, 0.f, 0.f, 0.f};

  const int wm = wid >> 1;        // wave row in 2x2 grid
  const int wn = wid & 1;
  const int frow = lane & 15;
  const int k16 = lane >> 4;
  int aoff[4];                    // A frag byte offsets
  int woffL[4], woffH[4];         // W frag lo/hi b128 byte offsets
#pragma unroll
  for (int f = 0; f < 4; ++f) {
    int ra = wm * 64 + f * 16 + frow;
    aoff[f] = ra * 64 + ((k16 ^ ((ra ^ (ra >> 2)) & 3)) * 16);
    int rw = wn * 64 + f * 16 + frow;
    woffL[f] = rw * 128 + (((2 * k16) ^ (rw & 7)) * 16);
    woffH[f] = rw * 128 + (((2 * k16 + 1) ^ (rw & 7)) * 16);
  }

  // ---- prologue: stage step 0 entirely via DMA ----
  async16(gpA[0], ldsb + ldsoffA[0]);
  async16(gpA[1], ldsb + ldsoffA[1]);
#pragma unroll
  for (int e = 0; e < 4; ++e) async16(gpW[e], ldsWf + ldsoffW[e]);
  __syncthreads();   // drains vmcnt(0): step-0 tiles visible

  for (int i = 0; i < NSTEP; ++i) {
    // ---- top: prefetch step i+1 into the idle buffers (async) ----
    const int dn = ((i + 1 < NSTEP) ? (i + 1) : i) * BK;   // clamped (safe reload)
    const uint32_t nbA = (uint32_t)(((i + 1) & 1) * 8192);
    const uint32_t nbW = (uint32_t)(((i + 1) & 1) * 16384);
    async16(gpA[0] + dn, ldsb + nbA + ldsoffA[0]);
    async16(gpA[1] + dn, ldsb + nbA + ldsoffA[1]);
#pragma unroll
    for (int e = 0; e < 4; ++e)
      async16(gpW[e] + dn, ldsWf + nbW + ldsoffW[e]);

    // ---- compute step i from buf[i&1] ----
    const uint32_t cbA = (uint32_t)((i & 1) * 8192);
    const uint32_t cbW = (uint32_t)((i & 1) * 16384);
    f16x8 aF[4];
#pragma unroll
    for (int f = 0; f < 4; ++f)
      aF[f] = *(const f16x8*)(ldsb + cbA + aoff[f]);
#pragma unroll
    for (int nf = 0; nf < 4; ++nf) {
      f32x4 lo = *(const f32x4*)(ldsWf + cbW + woffL[nf]);
      f32x4 hi = *(const f32x4*)(ldsWf + cbW + woffH[nf]);
      f16x8 wF;
      wF[0] = (_Float16)(lo[0] * lo[0]); wF[1] = (_Float16)(lo[1] * lo[1]);
      wF[2] = (_Float16)(lo[2] * lo[2]); wF[3] = (_Float16)(lo[3] * lo[3]);
      wF[4] = (_Float16)(hi[0] * hi[0]); wF[5] = (_Float16)(hi[1] * hi[1]);
      wF[6] = (_Float16)(hi[2] * hi[2]); wF[7] = (_Float16)(hi[3] * hi[3]);
#pragma unroll
      for (int mf = 0; mf < 4; ++mf)
        acc[mf][nf] = __builtin_amdgcn_mfma_f32_16x16x32_f16(aF[mf], wF, acc[mf][nf], 0, 0, 0);
    }

    __syncthreads();   // single barrier: drains DMA(i+1); step-i reads done
  }

  // ---- C write: row=(lane>>4)*4+r, col=lane&15 (verified gfx950 C/D layout) ----
  float* Gp = G + (size_t)ks * M_PAD_MF * K_;
  const int crow = m0 + wm * 64;
  const int ccol = n0 + wn * 64;
#pragma unroll
  for (int mf = 0; mf < 4; ++mf)
#pragma unroll
    for (int nf = 0; nf < 4; ++nf)
#pragma unroll
      for (int r = 0; r < 4; ++r) {
        int row = crow + mf * 16 + (lane >> 4) * 4 + r;
        int col = ccol + nf * 16 + (lane & 15);
        Gp[(size_t)row * K_ + col] = acc[mf][nf][r];
      }
}

// ---------------------------------------------------------------------------
// Epilogue: sum K-split planes, normalize, transpose-write.
// out[b][k][s] = -dot / (sqrt(pp)*sqrt(qq)*D)
// ---------------------------------------------------------------------------
__global__ __launch_bounds__(256)
void epilogue2(const float* __restrict__ G, float* __restrict__ out) {
  __shared__ float buf[256 * S_];
  const int tid = threadIdx.x;
  const int b = blockIdx.y;
  const int k0 = blockIdx.x * 256;
  const int k = k0 + tid;
  const float* G0 = G + (size_t)b * RPB * K_ + k;
  const float* G1 = G0 + (size_t)M_PAD_MF * K_;
  float nq = sqrtf(G0[20 * K_] + G1[20 * K_]);
#pragma unroll
  for (int s = 0; s < S_; ++s) {
    float dot = G0[s * K_] + G1[s * K_];
    float pp = G0[(S_ + s) * K_] + G1[(S_ + s) * K_];
    buf[tid * S_ + s] = -dot / (sqrtf(pp) * nq * (float)D_);
  }
  __syncthreads();
  float* ob = out + ((size_t)b * K_ + k0) * S_;
  for (int i = tid; i < 256 * S_; i += 256) ob[i] = buf[i];
}

// ===========================================================================
extern "C" void kernel_launch(void* const* d_in, const int* in_sizes, int n_in,
                              void* d_out, int out_size, void* d_ws, size_t ws_size,
                              hipStream_t stream) {
  const float* p = (const float*)d_in[0];
  const float* q = (const float*)d_in[1];
  const float* W = (const float*)d_in[2];
  float* out = (float*)d_out;

  // ws layout: Af [768][4096] f16 (6291456 B) | G [2][768][8192] f32 (50331648 B)
  uint8_t* w = (uint8_t*)d_ws;
  unsigned short* Af = (unsigned short*)w;
  float* G = (float*)(w + 6291456);

  build_a_f16<<<(M_PAD_MF * (D_ / 4)) / 256, 256, 0, stream>>>(p, q, Af);
  dim3 ggrid(K_ / BN, M_PAD_MF / BM, KSPLIT);   // (64, 6, 2) = 768 blocks = 3/CU
  gemm_mfma<<<ggrid, 256, 0, stream>>>(Af, W, G);
  epilogue2<<<dim3(K_ / 256, B_), 256, 0, stream>>>(G, out);
}

// Round 11
// 121.443 us; speedup vs baseline: 1.5714x; 1.0544x over previous
//
#include <hip/hip_runtime.h>
#include <stdint.h>

// Problem constants: B=32, S=10, D=4096, K=8192
#define B_ 32
#define S_ 10
#define D_ 4096
#define K_ 8192
#define RPB 21                 // rows per batch in A: 10 pq + 10 pp + 1 qq
#define M_REAL (B_ * RPB)      // 672

#define BM 256
#define BN 128
#define BK 32
#define M_PAD_MF 768           // 3 tiles of 256
#define KSPLIT 4
#define KCHUNK (D_ / KSPLIT)   // 1024
#define NSTEP (KCHUNK / BK)    // 32

typedef _Float16 f16x8 __attribute__((ext_vector_type(8)));
typedef float f32x4 __attribute__((ext_vector_type(4)));
typedef unsigned short us4 __attribute__((ext_vector_type(4)));

__device__ __forceinline__ void async16(const void* g, void* l) {
  __builtin_amdgcn_global_load_lds(
      (const __attribute__((address_space(1))) unsigned int*)g,
      (__attribute__((address_space(3))) unsigned int*)l, 16, 0, 0);
}

// ---------------------------------------------------------------------------
// Prepass: build A rows (pq / pp / qq), quantize to a single f16 plane.
// ---------------------------------------------------------------------------
__global__ __launch_bounds__(256)
void build_a_f16(const float* __restrict__ p, const float* __restrict__ q,
                 unsigned short* __restrict__ Af) {
  size_t idx = (size_t)blockIdx.x * 256 + threadIdx.x;  // over M_PAD_MF * 1024 float4s
  int d4 = (int)(idx & 1023);
  int m = (int)(idx >> 10);
  float4 v = make_float4(0.f, 0.f, 0.f, 0.f);
  if (m < M_REAL) {
    int b = m / RPB;
    int r = m - b * RPB;
    const float4* q4 = (const float4*)(q + (size_t)(b * S_ + (S_ - 1)) * D_);
    if (r < S_) {
      const float4* p4 = (const float4*)(p + (size_t)(b * S_ + r) * D_);
      float4 pv = p4[d4]; float4 qv = q4[d4];
      v = make_float4(pv.x * qv.x, pv.y * qv.y, pv.z * qv.z, pv.w * qv.w);
    } else if (r < 2 * S_) {
      const float4* p4 = (const float4*)(p + (size_t)(b * S_ + (r - S_)) * D_);
      float4 pv = p4[d4];
      v = make_float4(pv.x * pv.x, pv.y * pv.y, pv.z * pv.z, pv.w * pv.w);
    } else {
      float4 qv = q4[d4];
      v = make_float4(qv.x * qv.x, qv.y * qv.y, qv.z * qv.z, qv.w * qv.w);
    }
  }
  us4 h;
  ((unsigned short*)&h)[0] = (unsigned short)__builtin_bit_cast(unsigned short, (_Float16)v.x);
  ((unsigned short*)&h)[1] = (unsigned short)__builtin_bit_cast(unsigned short, (_Float16)v.y);
  ((unsigned short*)&h)[2] = (unsigned short)__builtin_bit_cast(unsigned short, (_Float16)v.z);
  ((unsigned short*)&h)[3] = (unsigned short)__builtin_bit_cast(unsigned short, (_Float16)v.w);
  ((us4*)Af)[idx] = h;
}

// ---------------------------------------------------------------------------
// Fused MFMA GEMM: G[ks][m][k] = sum_{d in chunk ks} Af[m][d] * (W[k][d])^2
// BIG-TILE variant: BM=256 x BN=128, 8 waves (4m x 2n), 512 threads, BK=32.
// Per-CU barrier-intervals: 96 (vs 192 at 128^2) — fatter intervals amortize
// the schedule-invariant ~1150cy interval cost; 2 blocks/CU (64KB LDS) give
// 16 waves/CU of TLP.
//   A (f16): global_load_lds, 2 issues/thread/step, pre-swizzled source.
//   W (f32): global_load_lds direct from fp32 input, 2 issues/thread/step;
//            square+cvt at FRAGMENT READ time (VALU co-issues with MFMA).
// Full double-buffer both operands, ONE __syncthreads per step (R6 skeleton).
// LDS 64 KB: Abuf0 @0 (16K) | Abuf1 @16K | Wbuf0 @32K (16K) | Wbuf1 @48K
// Swizzles (involutions, on DMA source and frag reads):
//   A row = 64 B  = 4 granules:  phys = g ^ ((row ^ (row>>2)) & 3)
//   W row = 128 B = 8 granules:  phys = g ^ (row & 7)
// ---------------------------------------------------------------------------
__global__ __launch_bounds__(512, 4)
void gemm_mfma(const unsigned short* __restrict__ Af, const float* __restrict__ W,
               float* __restrict__ G) {
  __shared__ unsigned short lds[32768];   // 64 KB
  const int tid = threadIdx.x;
  const int lane = tid & 63;
  const int wid = tid >> 6;               // 0..7
  const int m0 = blockIdx.y * BM;
  const int n0 = blockIdx.x * BN;
  const int ks = blockIdx.z;
  const int d_base = ks * KCHUNK;

  char* const ldsb = (char*)lds;          // A buffers at 0, 16384
  char* const ldsWf = ldsb + 32768;       // W f32 buffers at +0, +16384

  // ---- A staging: 2 async DMA issues/thread/step (16KB tile) ----
  const unsigned short* gpA[2];
  uint32_t ldsoffA[2];
#pragma unroll
  for (int e = 0; e < 2; ++e) {
    int c = e * 512 + tid;                // granule slot 0..1023
    int row = c >> 2;                     // 0..255
    int g = (tid & 3) ^ ((row ^ (row >> 2)) & 3);
    gpA[e] = Af + (size_t)(m0 + row) * D_ + d_base + g * 8;
    ldsoffA[e] = (uint32_t)(e * 8192 + wid * 1024);
  }

  // ---- W staging: 2 async DMA issues/thread/step (16KB fp32 tile) ----
  const float* gpW[2];
  uint32_t ldsoffW[2];
#pragma unroll
  for (int e = 0; e < 2; ++e) {
    int c = e * 512 + tid;
    int row = c >> 3;                     // 0..127
    int g = (tid & 7) ^ (row & 7);
    gpW[e] = W + (size_t)(n0 + row) * D_ + d_base + g * 4;
    ldsoffW[e] = (uint32_t)(e * 8192 + wid * 1024);
  }

  f32x4 acc[4][4];
#pragma unroll
  for (int i = 0; i < 4; ++i)
#pragma unroll
    for (int j = 0; j < 4; ++j) acc[i][j] = (f32x4){0.f, 0.f, 0.f, 0.f};

  const int wm = wid >> 1;        // 0..3 (m position)
  const int wn = wid & 1;         // 0..1 (n position)
  const int frow = lane & 15;
  const int k16 = lane >> 4;      // 0..3
  int aoff[4];                    // A frag byte offsets
  int woffL[4], woffH[4];         // W frag lo/hi b128 byte offsets
#pragma unroll
  for (int f = 0; f < 4; ++f) {
    int ra = wm * 64 + f * 16 + frow;                    // 0..255
    aoff[f] = ra * 64 + ((k16 ^ ((ra ^ (ra >> 2)) & 3)) * 16);
    int rw = wn * 64 + f * 16 + frow;                    // 0..127
    woffL[f] = rw * 128 + (((2 * k16) ^ (rw & 7)) * 16);
    woffH[f] = rw * 128 + (((2 * k16 + 1) ^ (rw & 7)) * 16);
  }

  // ---- prologue: stage step 0 entirely via DMA ----
  async16(gpA[0], ldsb + ldsoffA[0]);
  async16(gpA[1], ldsb + ldsoffA[1]);
  async16(gpW[0], ldsWf + ldsoffW[0]);
  async16(gpW[1], ldsWf + ldsoffW[1]);
  __syncthreads();   // drains vmcnt(0): step-0 tiles visible

  for (int i = 0; i < NSTEP; ++i) {
    // ---- top: prefetch step i+1 into the idle buffers (async) ----
    const int dn = ((i + 1 < NSTEP) ? (i + 1) : i) * BK;   // clamped (safe reload)
    const uint32_t nb = (uint32_t)(((i + 1) & 1) * 16384);
    async16(gpA[0] + dn, ldsb + nb + ldsoffA[0]);
    async16(gpA[1] + dn, ldsb + nb + ldsoffA[1]);
    async16(gpW[0] + dn, ldsWf + nb + ldsoffW[0]);
    async16(gpW[1] + dn, ldsWf + nb + ldsoffW[1]);

    // ---- compute step i from buf[i&1] ----
    const uint32_t cb = (uint32_t)((i & 1) * 16384);
    f16x8 aF[4];
#pragma unroll
    for (int f = 0; f < 4; ++f)
      aF[f] = *(const f16x8*)(ldsb + cb + aoff[f]);
#pragma unroll
    for (int nf = 0; nf < 4; ++nf) {
      f32x4 lo = *(const f32x4*)(ldsWf + cb + woffL[nf]);
      f32x4 hi = *(const f32x4*)(ldsWf + cb + woffH[nf]);
      f16x8 wF;
      wF[0] = (_Float16)(lo[0] * lo[0]); wF[1] = (_Float16)(lo[1] * lo[1]);
      wF[2] = (_Float16)(lo[2] * lo[2]); wF[3] = (_Float16)(lo[3] * lo[3]);
      wF[4] = (_Float16)(hi[0] * hi[0]); wF[5] = (_Float16)(hi[1] * hi[1]);
      wF[6] = (_Float16)(hi[2] * hi[2]); wF[7] = (_Float16)(hi[3] * hi[3]);
#pragma unroll
      for (int mf = 0; mf < 4; ++mf)
        acc[mf][nf] = __builtin_amdgcn_mfma_f32_16x16x32_f16(aF[mf], wF, acc[mf][nf], 0, 0, 0);
    }

    __syncthreads();   // single barrier: drains DMA(i+1); step-i reads done
  }

  // ---- C write: row=(lane>>4)*4+r, col=lane&15 (verified gfx950 C/D layout) ----
  float* Gp = G + (size_t)ks * M_PAD_MF * K_;
  const int crow = m0 + wm * 64;
  const int ccol = n0 + wn * 64;
#pragma unroll
  for (int mf = 0; mf < 4; ++mf)
#pragma unroll
    for (int nf = 0; nf < 4; ++nf)
#pragma unroll
      for (int r = 0; r < 4; ++r) {
        int row = crow + mf * 16 + (lane >> 4) * 4 + r;
        int col = ccol + nf * 16 + (lane & 15);
        Gp[(size_t)row * K_ + col] = acc[mf][nf][r];
      }
}

// ---------------------------------------------------------------------------
// Epilogue: sum 4 K-split planes, normalize, transpose-write.
// out[b][k][s] = -dot / (sqrt(pp)*sqrt(qq)*D)
// ---------------------------------------------------------------------------
__global__ __launch_bounds__(256)
void epilogue4(const float* __restrict__ G, float* __restrict__ out) {
  __shared__ float buf[256 * S_];
  const int tid = threadIdx.x;
  const int b = blockIdx.y;
  const int k0 = blockIdx.x * 256;
  const int k = k0 + tid;
  const size_t PL = (size_t)M_PAD_MF * K_;
  const float* Gb = G + (size_t)b * RPB * K_ + k;
  float nq = sqrtf(Gb[20 * K_] + Gb[PL + 20 * K_] + Gb[2 * PL + 20 * K_] + Gb[3 * PL + 20 * K_]);
#pragma unroll
  for (int s = 0; s < S_; ++s) {
    size_t od = (size_t)s * K_;
    size_t op = (size_t)(S_ + s) * K_;
    float dot = Gb[od] + Gb[PL + od] + Gb[2 * PL + od] + Gb[3 * PL + od];
    float pp  = Gb[op] + Gb[PL + op] + Gb[2 * PL + op] + Gb[3 * PL + op];
    buf[tid * S_ + s] = -dot / (sqrtf(pp) * nq * (float)D_);
  }
  __syncthreads();
  float* ob = out + ((size_t)b * K_ + k0) * S_;
  for (int i = tid; i < 256 * S_; i += 256) ob[i] = buf[i];
}

// ===========================================================================
extern "C" void kernel_launch(void* const* d_in, const int* in_sizes, int n_in,
                              void* d_out, int out_size, void* d_ws, size_t ws_size,
                              hipStream_t stream) {
  const float* p = (const float*)d_in[0];
  const float* q = (const float*)d_in[1];
  const float* W = (const float*)d_in[2];
  float* out = (float*)d_out;

  // ws layout: Af [768][4096] f16 (6291456 B) | G [4][768][8192] f32 (100663296 B)
  uint8_t* w = (uint8_t*)d_ws;
  unsigned short* Af = (unsigned short*)w;
  float* G = (float*)(w + 6291456);

  build_a_f16<<<(M_PAD_MF * (D_ / 4)) / 256, 256, 0, stream>>>(p, q, Af);
  dim3 ggrid(K_ / BN, M_PAD_MF / BM, KSPLIT);   // (64, 3, 4) = 768 blocks, 2/CU resident
  gemm_mfma<<<ggrid, 512, 0, stream>>>(Af, W, G);
  epilogue4<<<dim3(K_ / 256, B_), 256, 0, stream>>>(G, out);
}

// Round 12
// 120.476 us; speedup vs baseline: 1.5840x; 1.0080x over previous
//
#include <hip/hip_runtime.h>
#include <stdint.h>

// Problem constants: B=32, S=10, D=4096, K=8192
#define B_ 32
#define S_ 10
#define D_ 4096
#define K_ 8192
#define RPB 21                 // rows per batch in A: 10 pq + 10 pp + 1 qq
#define M_REAL (B_ * RPB)      // 672

#define BM 256
#define BN 128
#define BK 32
#define M_PAD_MF 768           // 3 tiles of 256
#define KSPLIT 4
#define KCHUNK (D_ / KSPLIT)   // 1024
#define NSTEP (KCHUNK / BK)    // 32

typedef _Float16 f16x8 __attribute__((ext_vector_type(8)));
typedef float f32x4 __attribute__((ext_vector_type(4)));
typedef unsigned short us4 __attribute__((ext_vector_type(4)));

__device__ __forceinline__ void async16(const void* g, void* l) {
  __builtin_amdgcn_global_load_lds(
      (const __attribute__((address_space(1))) unsigned int*)g,
      (__attribute__((address_space(3))) unsigned int*)l, 16, 0, 0);
}

// ---------------------------------------------------------------------------
// Prepass: build A rows (pq / pp / qq), quantize to a single f16 plane.
// ---------------------------------------------------------------------------
__global__ __launch_bounds__(256)
void build_a_f16(const float* __restrict__ p, const float* __restrict__ q,
                 unsigned short* __restrict__ Af) {
  size_t idx = (size_t)blockIdx.x * 256 + threadIdx.x;  // over M_PAD_MF * 1024 float4s
  int d4 = (int)(idx & 1023);
  int m = (int)(idx >> 10);
  float4 v = make_float4(0.f, 0.f, 0.f, 0.f);
  if (m < M_REAL) {
    int b = m / RPB;
    int r = m - b * RPB;
    const float4* q4 = (const float4*)(q + (size_t)(b * S_ + (S_ - 1)) * D_);
    if (r < S_) {
      const float4* p4 = (const float4*)(p + (size_t)(b * S_ + r) * D_);
      float4 pv = p4[d4]; float4 qv = q4[d4];
      v = make_float4(pv.x * qv.x, pv.y * qv.y, pv.z * qv.z, pv.w * qv.w);
    } else if (r < 2 * S_) {
      const float4* p4 = (const float4*)(p + (size_t)(b * S_ + (r - S_)) * D_);
      float4 pv = p4[d4];
      v = make_float4(pv.x * pv.x, pv.y * pv.y, pv.z * pv.z, pv.w * pv.w);
    } else {
      float4 qv = q4[d4];
      v = make_float4(qv.x * qv.x, qv.y * qv.y, qv.z * qv.z, qv.w * qv.w);
    }
  }
  us4 h;
  ((unsigned short*)&h)[0] = (unsigned short)__builtin_bit_cast(unsigned short, (_Float16)v.x);
  ((unsigned short*)&h)[1] = (unsigned short)__builtin_bit_cast(unsigned short, (_Float16)v.y);
  ((unsigned short*)&h)[2] = (unsigned short)__builtin_bit_cast(unsigned short, (_Float16)v.z);
  ((unsigned short*)&h)[3] = (unsigned short)__builtin_bit_cast(unsigned short, (_Float16)v.w);
  ((us4*)Af)[idx] = h;
}

// ---------------------------------------------------------------------------
// Fused MFMA GEMM: G[ks][m][k] = sum_{d in chunk ks} Af[m][d] * (W[k][d])^2
// BIG-TILE variant: BM=256 x BN=128, 8 waves (4m x 2n), 512 threads, BK=32.
// Per-CU barrier-intervals: 96 (vs 192 at 128^2) — fatter intervals amortize
// the schedule-invariant ~1150cy interval cost; 2 blocks/CU (64KB LDS) give
// 16 waves/CU of TLP.
//   A (f16): global_load_lds, 2 issues/thread/step, pre-swizzled source.
//   W (f32): global_load_lds direct from fp32 input, 2 issues/thread/step;
//            square+cvt at FRAGMENT READ time (VALU co-issues with MFMA).
// Full double-buffer both operands, ONE __syncthreads per step (R6 skeleton).
// LDS 64 KB: Abuf0 @0 (16K) | Abuf1 @16K | Wbuf0 @32K (16K) | Wbuf1 @48K
// Swizzles (involutions, on DMA source and frag reads):
//   A row = 64 B  = 4 granules:  phys = g ^ ((row ^ (row>>2)) & 3)
//   W row = 128 B = 8 granules:  phys = g ^ (row & 7)
// ---------------------------------------------------------------------------
__global__ __launch_bounds__(512, 4)
void gemm_mfma(const unsigned short* __restrict__ Af, const float* __restrict__ W,
               float* __restrict__ G) {
  __shared__ unsigned short lds[32768];   // 64 KB
  const int tid = threadIdx.x;
  const int lane = tid & 63;
  const int wid = tid >> 6;               // 0..7
  const int m0 = blockIdx.y * BM;
  const int n0 = blockIdx.x * BN;
  const int ks = blockIdx.z;
  const int d_base = ks * KCHUNK;

  char* const ldsb = (char*)lds;          // A buffers at 0, 16384
  char* const ldsWf = ldsb + 32768;       // W f32 buffers at +0, +16384

  // ---- A staging: 2 async DMA issues/thread/step (16KB tile) ----
  const unsigned short* gpA[2];
  uint32_t ldsoffA[2];
#pragma unroll
  for (int e = 0; e < 2; ++e) {
    int c = e * 512 + tid;                // granule slot 0..1023
    int row = c >> 2;                     // 0..255
    int g = (tid & 3) ^ ((row ^ (row >> 2)) & 3);
    gpA[e] = Af + (size_t)(m0 + row) * D_ + d_base + g * 8;
    ldsoffA[e] = (uint32_t)(e * 8192 + wid * 1024);
  }

  // ---- W staging: 2 async DMA issues/thread/step (16KB fp32 tile) ----
  const float* gpW[2];
  uint32_t ldsoffW[2];
#pragma unroll
  for (int e = 0; e < 2; ++e) {
    int c = e * 512 + tid;
    int row = c >> 3;                     // 0..127
    int g = (tid & 7) ^ (row & 7);
    gpW[e] = W + (size_t)(n0 + row) * D_ + d_base + g * 4;
    ldsoffW[e] = (uint32_t)(e * 8192 + wid * 1024);
  }

  f32x4 acc[4][4];
#pragma unroll
  for (int i = 0; i < 4; ++i)
#pragma unroll
    for (int j = 0; j < 4; ++j) acc[i][j] = (f32x4){0.f, 0.f, 0.f, 0.f};

  const int wm = wid >> 1;        // 0..3 (m position)
  const int wn = wid & 1;         // 0..1 (n position)
  const int frow = lane & 15;
  const int k16 = lane >> 4;      // 0..3
  int aoff[4];                    // A frag byte offsets
  int woffL[4], woffH[4];         // W frag lo/hi b128 byte offsets
#pragma unroll
  for (int f = 0; f < 4; ++f) {
    int ra = wm * 64 + f * 16 + frow;                    // 0..255
    aoff[f] = ra * 64 + ((k16 ^ ((ra ^ (ra >> 2)) & 3)) * 16);
    int rw = wn * 64 + f * 16 + frow;                    // 0..127
    woffL[f] = rw * 128 + (((2 * k16) ^ (rw & 7)) * 16);
    woffH[f] = rw * 128 + (((2 * k16 + 1) ^ (rw & 7)) * 16);
  }

  // ---- prologue: stage step 0 entirely via DMA ----
  async16(gpA[0], ldsb + ldsoffA[0]);
  async16(gpA[1], ldsb + ldsoffA[1]);
  async16(gpW[0], ldsWf + ldsoffW[0]);
  async16(gpW[1], ldsWf + ldsoffW[1]);
  __syncthreads();   // drains vmcnt(0): step-0 tiles visible

  for (int i = 0; i < NSTEP; ++i) {
    // ---- top: prefetch step i+1 into the idle buffers (async) ----
    const int dn = ((i + 1 < NSTEP) ? (i + 1) : i) * BK;   // clamped (safe reload)
    const uint32_t nb = (uint32_t)(((i + 1) & 1) * 16384);
    async16(gpA[0] + dn, ldsb + nb + ldsoffA[0]);
    async16(gpA[1] + dn, ldsb + nb + ldsoffA[1]);
    async16(gpW[0] + dn, ldsWf + nb + ldsoffW[0]);
    async16(gpW[1] + dn, ldsWf + nb + ldsoffW[1]);

    // ---- compute step i from buf[i&1] ----
    const uint32_t cb = (uint32_t)((i & 1) * 16384);
    f16x8 aF[4];
#pragma unroll
    for (int f = 0; f < 4; ++f)
      aF[f] = *(const f16x8*)(ldsb + cb + aoff[f]);
#pragma unroll
    for (int nf = 0; nf < 4; ++nf) {
      f32x4 lo = *(const f32x4*)(ldsWf + cb + woffL[nf]);
      f32x4 hi = *(const f32x4*)(ldsWf + cb + woffH[nf]);
      f16x8 wF;
      wF[0] = (_Float16)(lo[0] * lo[0]); wF[1] = (_Float16)(lo[1] * lo[1]);
      wF[2] = (_Float16)(lo[2] * lo[2]); wF[3] = (_Float16)(lo[3] * lo[3]);
      wF[4] = (_Float16)(hi[0] * hi[0]); wF[5] = (_Float16)(hi[1] * hi[1]);
      wF[6] = (_Float16)(hi[2] * hi[2]); wF[7] = (_Float16)(hi[3] * hi[3]);
#pragma unroll
      for (int mf = 0; mf < 4; ++mf)
        acc[mf][nf] = __builtin_amdgcn_mfma_f32_16x16x32_f16(aF[mf], wF, acc[mf][nf], 0, 0, 0);
    }

    __syncthreads();   // single barrier: drains DMA(i+1); step-i reads done
  }

  // ---- C write: row=(lane>>4)*4+r, col=lane&15 (verified gfx950 C/D layout) ----
  float* Gp = G + (size_t)ks * M_PAD_MF * K_;
  const int crow = m0 + wm * 64;
  const int ccol = n0 + wn * 64;
#pragma unroll
  for (int mf = 0; mf < 4; ++mf)
#pragma unroll
    for (int nf = 0; nf < 4; ++nf)
#pragma unroll
      for (int r = 0; r < 4; ++r) {
        int row = crow + mf * 16 + (lane >> 4) * 4 + r;
        int col = ccol + nf * 16 + (lane & 15);
        Gp[(size_t)row * K_ + col] = acc[mf][nf][r];
      }
}

// ---------------------------------------------------------------------------
// Epilogue: sum 4 K-split planes, normalize, transpose-write.
// out[b][k][s] = -dot / (sqrt(pp)*sqrt(qq)*D)
// ---------------------------------------------------------------------------
__global__ __launch_bounds__(256)
void epilogue4(const float* __restrict__ G, float* __restrict__ out) {
  __shared__ float buf[256 * S_];
  const int tid = threadIdx.x;
  const int b = blockIdx.y;
  const int k0 = blockIdx.x * 256;
  const int k = k0 + tid;
  const size_t PL = (size_t)M_PAD_MF * K_;
  const float* Gb = G + (size_t)b * RPB * K_ + k;
  float nq = sqrtf(Gb[20 * K_] + Gb[PL + 20 * K_] + Gb[2 * PL + 20 * K_] + Gb[3 * PL + 20 * K_]);
#pragma unroll
  for (int s = 0; s < S_; ++s) {
    size_t od = (size_t)s * K_;
    size_t op = (size_t)(S_ + s) * K_;
    float dot = Gb[od] + Gb[PL + od] + Gb[2 * PL + od] + Gb[3 * PL + od];
    float pp  = Gb[op] + Gb[PL + op] + Gb[2 * PL + op] + Gb[3 * PL + op];
    buf[tid * S_ + s] = -dot / (sqrtf(pp) * nq * (float)D_);
  }
  __syncthreads();
  float* ob = out + ((size_t)b * K_ + k0) * S_;
  for (int i = tid; i < 256 * S_; i += 256) ob[i] = buf[i];
}

// ===========================================================================
extern "C" void kernel_launch(void* const* d_in, const int* in_sizes, int n_in,
                              void* d_out, int out_size, void* d_ws, size_t ws_size,
                              hipStream_t stream) {
  const float* p = (const float*)d_in[0];
  const float* q = (const float*)d_in[1];
  const float* W = (const float*)d_in[2];
  float* out = (float*)d_out;

  // ws layout: Af [768][4096] f16 (6291456 B) | G [4][768][8192] f32 (100663296 B)
  uint8_t* w = (uint8_t*)d_ws;
  unsigned short* Af = (unsigned short*)w;
  float* G = (float*)(w + 6291456);

  build_a_f16<<<(M_PAD_MF * (D_ / 4)) / 256, 256, 0, stream>>>(p, q, Af);
  dim3 ggrid(K_ / BN, M_PAD_MF / BM, KSPLIT);   // (64, 3, 4) = 768 blocks, 2/CU resident
  gemm_mfma<<<ggrid, 512, 0, stream>>>(Af, W, G);
  epilogue4<<<dim3(K_ / 256, B_), 256, 0, stream>>>(G, out);
}